// Round 23
// baseline (47.787 us; speedup 1.0000x reference)
//
#include <hip/hip_runtime.h>
#include <hip/hip_bf16.h>

typedef __attribute__((ext_vector_type(4))) float f32x4;
typedef __attribute__((ext_vector_type(8))) short short8;
typedef __attribute__((ext_vector_type(4))) unsigned short ushort4v;
typedef _Float16 f16x8 __attribute__((ext_vector_type(8)));

#define NB 8
#define NN 2048
#define NF 128
#define LOG2E 1.4426950408889634f
#define MASK_NEG_H -60000.0f

static __device__ __forceinline__ unsigned short f2bf(float f) {
    union { __hip_bfloat16 b; unsigned short u; } cv;
    cv.b = __float2bfloat16(f);
    return cv.u;
}

static __device__ __forceinline__ void gload_lds16(const void* g, void* l) {
    __builtin_amdgcn_global_load_lds(
        (const __attribute__((address_space(1))) unsigned int*)g,
        (__attribute__((address_space(3))) unsigned int*)l, 16, 0, 0);
}

// ---------------------------------------------------------------------------
// Kernel PRE (fused): blocks 0..255 = hprime (h@W -> vfrag B-frags, si/sj);
// blocks 256..1279 = bias -> biasF A-frags (fp16).   (identical to R14-R19)
// ---------------------------------------------------------------------------
__global__ __launch_bounds__(256) void k_pre(
    const float* __restrict__ h, const int* __restrict__ adj,
    const float* __restrict__ dist, const float* __restrict__ W,
    const float* __restrict__ a, const float* __restrict__ scaler,
    unsigned short* __restrict__ vfrag, float* __restrict__ siC,
    float* __restrict__ sjC, _Float16* __restrict__ biasF)
{
    __shared__ __align__(16) unsigned char smem[34816];
    const int bid = blockIdx.x;
    const int t = threadIdx.x;

    if (bid < 256) {
        unsigned char* WT = smem;                  // 32KB swizzled W^T bf16
        float* wa1 = (float*)(smem + 32768);
        float* wa2 = wa1 + NF;

        const int lane = t & 63;
        const int w = t >> 6;
        const int b = bid >> 5;
        const int i0 = (bid & 31) << 6;

        {
            const int f = t >> 1;
            const int c0 = (t & 1) << 6;
            float s1 = 0.f, s2 = 0.f;
            const float* wrow = W + f * NF + c0;
            const float* a1p = a + c0;
            const float* a2p = a + NF + c0;
            #pragma unroll 8
            for (int c = 0; c < 64; ++c) {
                float wv = wrow[c];
                s1 += wv * a1p[c];
                s2 += wv * a2p[c];
                int col = c0 + c;
                int dst = col * 256 + ((2 * f) ^ ((col & 15) << 4));
                *reinterpret_cast<unsigned short*>(&WT[dst]) = f2bf(wv);
            }
            s1 += __shfl_xor(s1, 1);
            s2 += __shfl_xor(s2, 1);
            if ((t & 1) == 0) { wa1[f] = s1 * LOG2E; wa2[f] = s2 * LOG2E; }
        }
        __syncthreads();

        const int l15 = lane & 15;
        const int arow = i0 + w * 16 + l15;
        const int kofs = (lane >> 4) << 3;
        const float* hrow = h + (size_t)(b * NN + arow) * NF + kofs;
        const int swz = l15 << 4;

        f32x4 acc[8];
        #pragma unroll
        for (int nt = 0; nt < 8; ++nt) acc[nt] = (f32x4)(0.f);
        float s1 = 0.f, s2 = 0.f;

        #pragma unroll
        for (int k0 = 0; k0 < NF; k0 += 32) {
            f32x4 h0 = *reinterpret_cast<const f32x4*>(hrow + k0);
            f32x4 h1 = *reinterpret_cast<const f32x4*>(hrow + k0 + 4);
            f32x4 w1lo = *reinterpret_cast<const f32x4*>(&wa1[k0 + kofs]);
            f32x4 w1hi = *reinterpret_cast<const f32x4*>(&wa1[k0 + kofs + 4]);
            f32x4 w2lo = *reinterpret_cast<const f32x4*>(&wa2[k0 + kofs]);
            f32x4 w2hi = *reinterpret_cast<const f32x4*>(&wa2[k0 + kofs + 4]);
            short8 af;
            #pragma unroll
            for (int e = 0; e < 4; ++e) {
                s1 += h0[e] * w1lo[e] + h1[e] * w1hi[e];
                s2 += h0[e] * w2lo[e] + h1[e] * w2hi[e];
                af[e]     = (short)f2bf(h0[e]);
                af[4 + e] = (short)f2bf(h1[e]);
            }
            const int ib = (2 * (k0 + kofs)) ^ swz;
            #pragma unroll
            for (int nt = 0; nt < 8; ++nt) {
                short8 bf8 = *reinterpret_cast<short8*>(&WT[(nt * 16 + l15) * 256 + ib]);
                acc[nt] = __builtin_amdgcn_mfma_f32_16x16x32_bf16(af, bf8, acc[nt], 0, 0, 0);
            }
        }

        s1 += __shfl_xor(s1, 16); s1 += __shfl_xor(s1, 32);
        s2 += __shfl_xor(s2, 16); s2 += __shfl_xor(s2, 32);
        if (lane < 16) {
            siC[b * NN + arow] = s1;
            sjC[b * NN + arow] = s2;
        }

        const int J0 = i0 + w * 16 + ((lane >> 4) << 2);
        const int s = J0 >> 5;
        const int jq = (J0 >> 3) & 3;
        const int eh = J0 & 7;
        #pragma unroll
        for (int nt = 0; nt < 8; ++nt) {
            ushort4v pk;
            #pragma unroll
            for (int e = 0; e < 4; ++e) pk[e] = f2bf(acc[nt][e]);
            *reinterpret_cast<ushort4v*>(
                vfrag + (((size_t)(b * 64 + s) * 8 + nt) * 64 + (l15 | (jq << 4))) * 8 + eh) = pk;
        }
    } else {
        _Float16 (*st)[64][8] = (_Float16 (*)[64][8])smem;   // 8KB
        const int bid2 = bid - 256;
        const int iblk = bid2 >> 3;
        const int jch = bid2 & 7;
        const int i_l = t >> 4;
        const int o2 = t & 15;
        const int i = iblk * 16 + i_l;
        const int jbase = jch * 256 + o2 * 16;
        const float sc = scaler[0];

        const int* ap = adj + (size_t)i * NN + jbase;
        const float* dp = dist + (size_t)i * NN + jbase;
        int av[16]; float dv[16];
        *reinterpret_cast<int4*>(&av[0])  = *reinterpret_cast<const int4*>(ap);
        *reinterpret_cast<int4*>(&av[4])  = *reinterpret_cast<const int4*>(ap + 4);
        *reinterpret_cast<int4*>(&av[8])  = *reinterpret_cast<const int4*>(ap + 8);
        *reinterpret_cast<int4*>(&av[12]) = *reinterpret_cast<const int4*>(ap + 12);
        *reinterpret_cast<float4*>(&dv[0])  = *reinterpret_cast<const float4*>(dp);
        *reinterpret_cast<float4*>(&dv[4])  = *reinterpret_cast<const float4*>(dp + 4);
        *reinterpret_cast<float4*>(&dv[8])  = *reinterpret_cast<const float4*>(dp + 8);
        *reinterpret_cast<float4*>(&dv[12]) = *reinterpret_cast<const float4*>(dp + 12);

        #pragma unroll
        for (int u = 0; u < 2; ++u) {
            const int sl = (o2 * 2 + u) >> 2;
            const int jq = (o2 * 2 + u) & 3;
            f16x8 pk;
            #pragma unroll
            for (int e = 0; e < 8; ++e) {
                const int idx = u * 8 + e;
                float v = (av[idx] > 0) ? (-__log2f(dv[idx] + 1e-6f) * sc) : MASK_NEG_H;
                pk[e] = (_Float16)v;
            }
            *reinterpret_cast<f16x8*>(&st[sl][i_l | (jq << 4)][0]) = pk;
        }
        __syncthreads();

        const int w = t >> 6, lane = t & 63;
        #pragma unroll
        for (int sub = 0; sub < 2; ++sub) {
            const int fs = w * 2 + sub;
            *reinterpret_cast<f16x8*>(
                biasF + ((size_t)(iblk * 64 + jch * 8 + fs) * 64 + lane) * 8) =
                *reinterpret_cast<f16x8*>(&st[fs][lane][0]);
        }
    }
}

// ---------------------------------------------------------------------------
// Kernel C: R19 (best: depth-3 counted V pipeline, 64-row block, one barrier
// per tile) + T5 s_setprio(1) around each QSTEP's MFMA cluster — the single
// isolated change this round.
// ---------------------------------------------------------------------------
__global__ __launch_bounds__(512) void k_attn(
    const unsigned short* __restrict__ vfrag, const float* __restrict__ siC,
    const float* __restrict__ sjC, const _Float16* __restrict__ biasF,
    float* __restrict__ out)
{
    __shared__ __align__(16) unsigned char vbuf[4][32768];  // 128KB
    __shared__ float lp[2][4][16];

    const int t = threadIdx.x;
    const int lane = t & 63;
    const int w = t >> 6;          // 0..7
    const int rt = w & 3;          // 16-row tile
    const int jh = w >> 2;         // 64-j half of each 128-j tile
    const int l15 = lane & 15;
    const int hi = lane >> 4;

    const int b = blockIdx.x & 7;   // XCD = batch
    const int rg = blockIdx.x >> 3; // 64-row group 0..31

    const int rowbase = rg * 64 + rt * 16;
    const float si0 = siC[b * NN + rowbase + l15];

    const unsigned short* vsrc = vfrag + (size_t)b * 262144 + w * 512 + lane * 8;
    const int ldst = w * 1024;

    const _Float16* bp = biasF + ((size_t)((rg * 4 + rt) * 64) * 64 + lane) * 8;
    const float* sjb = sjC + b * NN + hi * 8;

    f32x4 acc[8];
    #pragma unroll
    for (int ct = 0; ct < 8; ++ct) acc[ct] = (f32x4)(0.f);
    float ls0 = 0.f;

#define STAGE(TL, BUF)                                                        \
    { const unsigned short* gs = vsrc + (TL) * 16384;                         \
      unsigned char* lb = &vbuf[BUF][ldst];                                   \
      gload_lds16(gs,         lb);                                            \
      gload_lds16(gs + 4096,  lb + 8192);                                     \
      gload_lds16(gs + 8192,  lb + 16384);                                    \
      gload_lds16(gs + 12288, lb + 24576); }

    f32x4 sjA0, sjA1, sjB0, sjB1;
    f16x8 bvA, bvB;

#define PREFETCH_SB(TL)                                                       \
    { const int sA = (TL) * 4 + jh * 2;                                       \
      sjA0 = *reinterpret_cast<const f32x4*>(sjb + sA * 32);                  \
      sjA1 = *reinterpret_cast<const f32x4*>(sjb + sA * 32 + 4);              \
      bvA  = *reinterpret_cast<const f16x8*>(bp + sA * 512);                  \
      sjB0 = *reinterpret_cast<const f32x4*>(sjb + sA * 32 + 32);             \
      sjB1 = *reinterpret_cast<const f32x4*>(sjb + sA * 32 + 36);             \
      bvB  = *reinterpret_cast<const f16x8*>(bp + sA * 512 + 512); }

#define QSTEP(SJ0, SJ1, BV, LSL, BUF)                                         \
    { short8 pa;                                                              \
      _Pragma("unroll")                                                       \
      for (int e = 0; e < 8; ++e) {                                           \
          const float sjv = (e < 4) ? SJ0[e] : SJ1[e - 4];                    \
          float x = si0 + sjv;                                                \
          x = fmaxf(x, 0.2f * x) + (float)BV[e];                              \
          float p = __builtin_amdgcn_exp2f(x);                                \
          ls0 += p;                                                           \
          pa[e] = (short)f2bf(p);                                             \
      }                                                                       \
      __builtin_amdgcn_s_setprio(1);                                          \
      _Pragma("unroll")                                                       \
      for (int ct = 0; ct < 8; ++ct) {                                        \
          const short8 bfr = *reinterpret_cast<const short8*>(                \
              &vbuf[BUF][((LSL) * 8 + ct) * 1024 + lane * 16]);               \
          acc[ct] = __builtin_amdgcn_mfma_f32_16x16x32_bf16(pa, bfr, acc[ct], 0, 0, 0); \
      }                                                                       \
      __builtin_amdgcn_s_setprio(0); }

    // prologue: g0, bias0, g1, g2  (queue order = the ledger)
    STAGE(0, 0)
    PREFETCH_SB(0)
    asm volatile("" ::: "memory");
    STAGE(1, 1)
    STAGE(2, 2)

    for (int tl = 0; tl < 15; ++tl) {
        const int buf = tl & 3;
        // steady queue: S(tl)4, PF(tl)6, S(tl+1)4, S(tl+2)4 -> retire S(tl)
        if (tl < 14) {
            asm volatile("s_waitcnt vmcnt(14)" ::: "memory");
        } else {
            asm volatile("s_waitcnt vmcnt(10)" ::: "memory");
        }
        __builtin_amdgcn_s_barrier();
        QSTEP(sjA0, sjA1, bvA, jh * 2, buf)
        QSTEP(sjB0, sjB1, bvB, jh * 2 + 1, buf)
        PREFETCH_SB(tl + 1)
        asm volatile("" ::: "memory");
        if (tl < 13) STAGE(tl + 3, (tl + 3) & 3)
    }
    {   // peeled tl = 15: outstanding = S(15)4, PF(15)6
        asm volatile("s_waitcnt vmcnt(6)" ::: "memory");
        __builtin_amdgcn_s_barrier();
        QSTEP(sjA0, sjA1, bvA, jh * 2, 3)
        QSTEP(sjB0, sjB1, bvB, jh * 2 + 1, 3)
    }
#undef STAGE
#undef PREFETCH_SB
#undef QSTEP

    // ---- combine jh halves (reuse vbuf[1] as fp32 red buffer) ----
    ls0 += __shfl_xor(ls0, 16);
    ls0 += __shfl_xor(ls0, 32);
    if (lane < 16) lp[jh][rt][l15] = ls0;
    __syncthreads();

    if (jh == 1) {
        #pragma unroll
        for (int ct = 0; ct < 8; ++ct)
            *reinterpret_cast<f32x4*>(&vbuf[1][(rt * 8 + ct) * 1024 + lane * 16]) = acc[ct];
    }
    __syncthreads();
    if (jh == 0) {
        float linv[4];
        #pragma unroll
        for (int e = 0; e < 4; ++e) {
            const int rr = (hi << 2) + e;
            linv[e] = 1.0f / (lp[0][rt][rr] + lp[1][rt][rr]);
        }
        #pragma unroll
        for (int ct = 0; ct < 8; ++ct) {
            f32x4 o = acc[ct] + *reinterpret_cast<const f32x4*>(
                &vbuf[1][(rt * 8 + ct) * 1024 + lane * 16]);
            const int col = ct * 16 + l15;
            #pragma unroll
            for (int e = 0; e < 4; ++e) {
                const int row = rowbase + (hi << 2) + e;
                float v = o[e] * linv[e];
                v = (v > 0.f) ? v : expm1f(v);
                out[(size_t)(b * NN + row) * NF + col] = v;
            }
        }
    }
}

extern "C" void kernel_launch(void* const* d_in, const int* in_sizes, int n_in,
                              void* d_out, int out_size, void* d_ws, size_t ws_size,
                              hipStream_t stream) {
    (void)in_sizes; (void)n_in; (void)out_size; (void)ws_size;
    const float* h      = (const float*)d_in[0];
    const int*   adj    = (const int*)d_in[1];
    const float* dist   = (const float*)d_in[2];
    const float* W      = (const float*)d_in[3];
    const float* a      = (const float*)d_in[4];
    const float* scaler = (const float*)d_in[5];
    float* out = (float*)d_out;

    char* ws = (char*)d_ws;
    unsigned short* vfrag = (unsigned short*)ws;                     // 4 MiB
    float* siC      = (float*)(ws + 4 * 1024 * 1024);                // 64 KiB
    float* sjC      = (float*)(ws + 4 * 1024 * 1024 + 65536);        // 64 KiB
    _Float16* biasF = (_Float16*)(ws + 4 * 1024 * 1024 + 2 * 65536); // 8 MiB

    k_pre<<<dim3(1280), dim3(256), 0, stream>>>(h, adj, dist, W, a, scaler,
                                                vfrag, siC, sjC, biasF);
    k_attn<<<dim3(NB * NN / 64), dim3(512), 0, stream>>>(vfrag, siC, sjC, biasF, out);
}

// Round 24
// 41.214 us; speedup vs baseline: 1.1595x; 1.1595x over previous
//
#include <hip/hip_runtime.h>
#include <hip/hip_bf16.h>

typedef __attribute__((ext_vector_type(4))) float f32x4;
typedef __attribute__((ext_vector_type(8))) short short8;
typedef __attribute__((ext_vector_type(4))) unsigned short ushort4v;
typedef _Float16 f16x8 __attribute__((ext_vector_type(8)));

#define NB 8
#define NN 2048
#define NF 128
#define LOG2E 1.4426950408889634f
#define MASK_NEG_H -60000.0f

static __device__ __forceinline__ unsigned short f2bf(float f) {
    union { __hip_bfloat16 b; unsigned short u; } cv;
    cv.b = __float2bfloat16(f);
    return cv.u;
}

static __device__ __forceinline__ void gload_lds16(const void* g, void* l) {
    __builtin_amdgcn_global_load_lds(
        (const __attribute__((address_space(1))) unsigned int*)g,
        (__attribute__((address_space(3))) unsigned int*)l, 16, 0, 0);
}

// ---------------------------------------------------------------------------
// Kernel PRE (fused): blocks 0..255 = hprime (h@W -> vfrag B-frags, si/sj);
// blocks 256..1279 = bias -> biasF A-frags (fp16).
// ---------------------------------------------------------------------------
__global__ __launch_bounds__(256) void k_pre(
    const float* __restrict__ h, const int* __restrict__ adj,
    const float* __restrict__ dist, const float* __restrict__ W,
    const float* __restrict__ a, const float* __restrict__ scaler,
    unsigned short* __restrict__ vfrag, float* __restrict__ siC,
    float* __restrict__ sjC, _Float16* __restrict__ biasF)
{
    __shared__ __align__(16) unsigned char smem[34816];
    const int bid = blockIdx.x;
    const int t = threadIdx.x;

    if (bid < 256) {
        unsigned char* WT = smem;                  // 32KB swizzled W^T bf16
        float* wa1 = (float*)(smem + 32768);
        float* wa2 = wa1 + NF;

        const int lane = t & 63;
        const int w = t >> 6;
        const int b = bid >> 5;
        const int i0 = (bid & 31) << 6;

        {
            const int f = t >> 1;
            const int c0 = (t & 1) << 6;
            float s1 = 0.f, s2 = 0.f;
            const float* wrow = W + f * NF + c0;
            const float* a1p = a + c0;
            const float* a2p = a + NF + c0;
            #pragma unroll 8
            for (int c = 0; c < 64; ++c) {
                float wv = wrow[c];
                s1 += wv * a1p[c];
                s2 += wv * a2p[c];
                int col = c0 + c;
                int dst = col * 256 + ((2 * f) ^ ((col & 15) << 4));
                *reinterpret_cast<unsigned short*>(&WT[dst]) = f2bf(wv);
            }
            s1 += __shfl_xor(s1, 1);
            s2 += __shfl_xor(s2, 1);
            if ((t & 1) == 0) { wa1[f] = s1 * LOG2E; wa2[f] = s2 * LOG2E; }
        }
        __syncthreads();

        const int l15 = lane & 15;
        const int arow = i0 + w * 16 + l15;
        const int kofs = (lane >> 4) << 3;
        const float* hrow = h + (size_t)(b * NN + arow) * NF + kofs;
        const int swz = l15 << 4;

        f32x4 acc[8];
        #pragma unroll
        for (int nt = 0; nt < 8; ++nt) acc[nt] = (f32x4)(0.f);
        float s1 = 0.f, s2 = 0.f;

        #pragma unroll
        for (int k0 = 0; k0 < NF; k0 += 32) {
            f32x4 h0 = *reinterpret_cast<const f32x4*>(hrow + k0);
            f32x4 h1 = *reinterpret_cast<const f32x4*>(hrow + k0 + 4);
            f32x4 w1lo = *reinterpret_cast<const f32x4*>(&wa1[k0 + kofs]);
            f32x4 w1hi = *reinterpret_cast<const f32x4*>(&wa1[k0 + kofs + 4]);
            f32x4 w2lo = *reinterpret_cast<const f32x4*>(&wa2[k0 + kofs]);
            f32x4 w2hi = *reinterpret_cast<const f32x4*>(&wa2[k0 + kofs + 4]);
            short8 af;
            #pragma unroll
            for (int e = 0; e < 4; ++e) {
                s1 += h0[e] * w1lo[e] + h1[e] * w1hi[e];
                s2 += h0[e] * w2lo[e] + h1[e] * w2hi[e];
                af[e]     = (short)f2bf(h0[e]);
                af[4 + e] = (short)f2bf(h1[e]);
            }
            const int ib = (2 * (k0 + kofs)) ^ swz;
            #pragma unroll
            for (int nt = 0; nt < 8; ++nt) {
                short8 bf8 = *reinterpret_cast<short8*>(&WT[(nt * 16 + l15) * 256 + ib]);
                acc[nt] = __builtin_amdgcn_mfma_f32_16x16x32_bf16(af, bf8, acc[nt], 0, 0, 0);
            }
        }

        s1 += __shfl_xor(s1, 16); s1 += __shfl_xor(s1, 32);
        s2 += __shfl_xor(s2, 16); s2 += __shfl_xor(s2, 32);
        if (lane < 16) {
            siC[b * NN + arow] = s1;
            sjC[b * NN + arow] = s2;
        }

        const int J0 = i0 + w * 16 + ((lane >> 4) << 2);
        const int s = J0 >> 5;
        const int jq = (J0 >> 3) & 3;
        const int eh = J0 & 7;
        #pragma unroll
        for (int nt = 0; nt < 8; ++nt) {
            ushort4v pk;
            #pragma unroll
            for (int e = 0; e < 4; ++e) pk[e] = f2bf(acc[nt][e]);
            *reinterpret_cast<ushort4v*>(
                vfrag + (((size_t)(b * 64 + s) * 8 + nt) * 64 + (l15 | (jq << 4))) * 8 + eh) = pk;
        }
    } else {
        _Float16 (*st)[64][8] = (_Float16 (*)[64][8])smem;   // 8KB
        const int bid2 = bid - 256;
        const int iblk = bid2 >> 3;
        const int jch = bid2 & 7;
        const int i_l = t >> 4;
        const int o2 = t & 15;
        const int i = iblk * 16 + i_l;
        const int jbase = jch * 256 + o2 * 16;
        const float sc = scaler[0];

        const int* ap = adj + (size_t)i * NN + jbase;
        const float* dp = dist + (size_t)i * NN + jbase;
        int av[16]; float dv[16];
        *reinterpret_cast<int4*>(&av[0])  = *reinterpret_cast<const int4*>(ap);
        *reinterpret_cast<int4*>(&av[4])  = *reinterpret_cast<const int4*>(ap + 4);
        *reinterpret_cast<int4*>(&av[8])  = *reinterpret_cast<const int4*>(ap + 8);
        *reinterpret_cast<int4*>(&av[12]) = *reinterpret_cast<const int4*>(ap + 12);
        *reinterpret_cast<float4*>(&dv[0])  = *reinterpret_cast<const float4*>(dp);
        *reinterpret_cast<float4*>(&dv[4])  = *reinterpret_cast<const float4*>(dp + 4);
        *reinterpret_cast<float4*>(&dv[8])  = *reinterpret_cast<const float4*>(dp + 8);
        *reinterpret_cast<float4*>(&dv[12]) = *reinterpret_cast<const float4*>(dp + 12);

        #pragma unroll
        for (int u = 0; u < 2; ++u) {
            const int sl = (o2 * 2 + u) >> 2;
            const int jq = (o2 * 2 + u) & 3;
            f16x8 pk;
            #pragma unroll
            for (int e = 0; e < 8; ++e) {
                const int idx = u * 8 + e;
                float v = (av[idx] > 0) ? (-__log2f(dv[idx] + 1e-6f) * sc) : MASK_NEG_H;
                pk[e] = (_Float16)v;
            }
            *reinterpret_cast<f16x8*>(&st[sl][i_l | (jq << 4)][0]) = pk;
        }
        __syncthreads();

        const int w = t >> 6, lane = t & 63;
        #pragma unroll
        for (int sub = 0; sub < 2; ++sub) {
            const int fs = w * 2 + sub;
            *reinterpret_cast<f16x8*>(
                biasF + ((size_t)(iblk * 64 + jch * 8 + fs) * 64 + lane) * 8) =
                *reinterpret_cast<f16x8*>(&st[fs][lane][0]);
        }
    }
}

// ---------------------------------------------------------------------------
// Kernel C (R19, measured best = 41.5µs total): depth-3 counted V pipeline.
// Block = 64 rows x 128 cols, grid 256 (XCD = batch). V staged via
// global_load_lds into 4x32KB LDS buffers, 3 tiles ahead. Ledger: steady
// top-of-tile queue = S(t)4 + PF(t)6 + S(t+1)4 + S(t+2)4 -> vmcnt(14)
// retires exactly S(t); t=14 -> vmcnt(10); peeled t=15 -> vmcnt(6).
// bias/sj reg-prefetched 1 tile ahead, issued before the STAGE. One barrier
// per tile (bottom barrier removed; proven redundant, R19).
// ---------------------------------------------------------------------------
__global__ __launch_bounds__(512) void k_attn(
    const unsigned short* __restrict__ vfrag, const float* __restrict__ siC,
    const float* __restrict__ sjC, const _Float16* __restrict__ biasF,
    float* __restrict__ out)
{
    __shared__ __align__(16) unsigned char vbuf[4][32768];  // 128KB
    __shared__ float lp[2][4][16];

    const int t = threadIdx.x;
    const int lane = t & 63;
    const int w = t >> 6;          // 0..7
    const int rt = w & 3;          // 16-row tile
    const int jh = w >> 2;         // 64-j half of each 128-j tile
    const int l15 = lane & 15;
    const int hi = lane >> 4;

    const int b = blockIdx.x & 7;   // XCD = batch
    const int rg = blockIdx.x >> 3; // 64-row group 0..31

    const int rowbase = rg * 64 + rt * 16;
    const float si0 = siC[b * NN + rowbase + l15];

    const unsigned short* vsrc = vfrag + (size_t)b * 262144 + w * 512 + lane * 8;
    const int ldst = w * 1024;

    const _Float16* bp = biasF + ((size_t)((rg * 4 + rt) * 64) * 64 + lane) * 8;
    const float* sjb = sjC + b * NN + hi * 8;

    f32x4 acc[8];
    #pragma unroll
    for (int ct = 0; ct < 8; ++ct) acc[ct] = (f32x4)(0.f);
    float ls0 = 0.f;

#define STAGE(TL, BUF)                                                        \
    { const unsigned short* gs = vsrc + (TL) * 16384;                         \
      unsigned char* lb = &vbuf[BUF][ldst];                                   \
      gload_lds16(gs,         lb);                                            \
      gload_lds16(gs + 4096,  lb + 8192);                                     \
      gload_lds16(gs + 8192,  lb + 16384);                                    \
      gload_lds16(gs + 12288, lb + 24576); }

    f32x4 sjA0, sjA1, sjB0, sjB1;
    f16x8 bvA, bvB;

#define PREFETCH_SB(TL)                                                       \
    { const int sA = (TL) * 4 + jh * 2;                                       \
      sjA0 = *reinterpret_cast<const f32x4*>(sjb + sA * 32);                  \
      sjA1 = *reinterpret_cast<const f32x4*>(sjb + sA * 32 + 4);              \
      bvA  = *reinterpret_cast<const f16x8*>(bp + sA * 512);                  \
      sjB0 = *reinterpret_cast<const f32x4*>(sjb + sA * 32 + 32);             \
      sjB1 = *reinterpret_cast<const f32x4*>(sjb + sA * 32 + 36);             \
      bvB  = *reinterpret_cast<const f16x8*>(bp + sA * 512 + 512); }

#define QSTEP(SJ0, SJ1, BV, LSL, BUF)                                         \
    { short8 pa;                                                              \
      _Pragma("unroll")                                                       \
      for (int e = 0; e < 8; ++e) {                                           \
          const float sjv = (e < 4) ? SJ0[e] : SJ1[e - 4];                    \
          float x = si0 + sjv;                                                \
          x = fmaxf(x, 0.2f * x) + (float)BV[e];                              \
          float p = __builtin_amdgcn_exp2f(x);                                \
          ls0 += p;                                                           \
          pa[e] = (short)f2bf(p);                                             \
      }                                                                       \
      _Pragma("unroll")                                                       \
      for (int ct = 0; ct < 8; ++ct) {                                        \
          const short8 bfr = *reinterpret_cast<const short8*>(                \
              &vbuf[BUF][((LSL) * 8 + ct) * 1024 + lane * 16]);               \
          acc[ct] = __builtin_amdgcn_mfma_f32_16x16x32_bf16(pa, bfr, acc[ct], 0, 0, 0); \
      } }

    // prologue: g0, bias0, g1, g2  (queue order = the ledger)
    STAGE(0, 0)
    PREFETCH_SB(0)
    asm volatile("" ::: "memory");
    STAGE(1, 1)
    STAGE(2, 2)

    for (int tl = 0; tl < 15; ++tl) {
        const int buf = tl & 3;
        // steady queue: S(tl)4, PF(tl)6, S(tl+1)4, S(tl+2)4 -> retire S(tl)
        if (tl < 14) {
            asm volatile("s_waitcnt vmcnt(14)" ::: "memory");
        } else {
            asm volatile("s_waitcnt vmcnt(10)" ::: "memory");
        }
        __builtin_amdgcn_s_barrier();
        QSTEP(sjA0, sjA1, bvA, jh * 2, buf)
        QSTEP(sjB0, sjB1, bvB, jh * 2 + 1, buf)
        PREFETCH_SB(tl + 1)
        asm volatile("" ::: "memory");
        if (tl < 13) STAGE(tl + 3, (tl + 3) & 3)
    }
    {   // peeled tl = 15: outstanding = S(15)4, PF(15)6
        asm volatile("s_waitcnt vmcnt(6)" ::: "memory");
        __builtin_amdgcn_s_barrier();
        QSTEP(sjA0, sjA1, bvA, jh * 2, 3)
        QSTEP(sjB0, sjB1, bvB, jh * 2 + 1, 3)
    }
#undef STAGE
#undef PREFETCH_SB
#undef QSTEP

    // ---- combine jh halves (reuse vbuf[1] as fp32 red buffer) ----
    ls0 += __shfl_xor(ls0, 16);
    ls0 += __shfl_xor(ls0, 32);
    if (lane < 16) lp[jh][rt][l15] = ls0;
    __syncthreads();

    if (jh == 1) {
        #pragma unroll
        for (int ct = 0; ct < 8; ++ct)
            *reinterpret_cast<f32x4*>(&vbuf[1][(rt * 8 + ct) * 1024 + lane * 16]) = acc[ct];
    }
    __syncthreads();
    if (jh == 0) {
        float linv[4];
        #pragma unroll
        for (int e = 0; e < 4; ++e) {
            const int rr = (hi << 2) + e;
            linv[e] = 1.0f / (lp[0][rt][rr] + lp[1][rt][rr]);
        }
        #pragma unroll
        for (int ct = 0; ct < 8; ++ct) {
            f32x4 o = acc[ct] + *reinterpret_cast<const f32x4*>(
                &vbuf[1][(rt * 8 + ct) * 1024 + lane * 16]);
            const int col = ct * 16 + l15;
            #pragma unroll
            for (int e = 0; e < 4; ++e) {
                const int row = rowbase + (hi << 2) + e;
                float v = o[e] * linv[e];
                v = (v > 0.f) ? v : expm1f(v);
                out[(size_t)(b * NN + row) * NF + col] = v;
            }
        }
    }
}

extern "C" void kernel_launch(void* const* d_in, const int* in_sizes, int n_in,
                              void* d_out, int out_size, void* d_ws, size_t ws_size,
                              hipStream_t stream) {
    (void)in_sizes; (void)n_in; (void)out_size; (void)ws_size;
    const float* h      = (const float*)d_in[0];
    const int*   adj    = (const int*)d_in[1];
    const float* dist   = (const float*)d_in[2];
    const float* W      = (const float*)d_in[3];
    const float* a      = (const float*)d_in[4];
    const float* scaler = (const float*)d_in[5];
    float* out = (float*)d_out;

    char* ws = (char*)d_ws;
    unsigned short* vfrag = (unsigned short*)ws;                     // 4 MiB
    float* siC      = (float*)(ws + 4 * 1024 * 1024);                // 64 KiB
    float* sjC      = (float*)(ws + 4 * 1024 * 1024 + 65536);        // 64 KiB
    _Float16* biasF = (_Float16*)(ws + 4 * 1024 * 1024 + 2 * 65536); // 8 MiB

    k_pre<<<dim3(1280), dim3(256), 0, stream>>>(h, adj, dist, W, a, scaler,
                                                vfrag, siC, sjC, biasF);
    k_attn<<<dim3(NB * NN / 64), dim3(512), 0, stream>>>(vfrag, siC, sjC, biasF, out);
}